// Round 3
// baseline (94.398 us; speedup 1.0000x reference)
//
#include <hip/hip_runtime.h>

// ResidualBlock2 (AdderNet): two adder-convs + BN + ReLU + residual.
// N=32, C=32, H=W=32, K=3. No multiplies in the conv -> no MFMA; pure VALU.
// R3: 3-kernel structure. Quantize folded into weight staging. BN coefs
// computed redundantly per block (deterministic). Conv uses transposed
// (column-major) x tile in LDS with XOR-swizzled 16B blocks so each lane
// reads its 6-row column strip as ds_read_b128 + ds_read_b64.
// Per lane: 4 output rows x 2 co. 512 blocks x 256 thr, 2 blocks/CU.

#define QSCALE (2.5f / 127.f)

__device__ __forceinline__ float quant(float w) {
  float v = rintf(w * (1.0f / QSCALE));     // round-half-even = jnp.round
  v = fminf(fmaxf(v, -127.f), 127.f);
  return v * QSCALE;
}

// grid 512 = 32 n x 4 rowgroups(8 rows) x 4 co-octets; 256 thr = 4 waves.
// wave wv handles co pair (oct*8 + wv*2 + {0,1}); lane: col = l&31,
// rowquad rq = l>>5 (output rows h0+4rq .. +3).
template <bool AFFINE>
__global__ __launch_bounds__(256, 2) void conv_k(
    const float* __restrict__ in,      // [32][32][32][32] conv input
    const float* __restrict__ wraw,    // this conv's raw weights [32][32][3][3]
    const float* __restrict__ ps_prev, // [32][128] prev conv partial sums
    const float* __restrict__ pq_prev, // [32][128] prev conv partial sumsq
    const float* __restrict__ wprev,   // prev conv raw weights (for wb)
    const float* __restrict__ gprev,   // prev gamma
    const float* __restrict__ bprev,   // prev beta
    float* __restrict__ outb,          // raw conv out [32][32][32][32]
    float* __restrict__ ps_out,        // [32][128]
    float* __restrict__ pq_out) {      // [32][128]
  // x tile: [ci][34 cols][16 words], word r <-> global row h0-1+r (r<12 used)
  __shared__ __align__(16) float xs[32 * 34 * 16];   // 69632 B
  __shared__ __align__(16) float wls[4 * 32 * 20];   // 10240 B (co-pair layout)
  __shared__ float abuf[32], bbuf[32];

  const int tid = threadIdx.x;
  const int blk = blockIdx.x;
  const int n = blk >> 4, rg = (blk >> 2) & 3, oct = blk & 3;
  const int h0 = rg * 8;

  if (AFFINE) {
    // Redundant per-block BN1 fold: a = g/sqrt(var+eps), b = beta + wb - a*mu.
    // Scratch reuses xs (done before staging).
    double* sred = (double*)xs;             // [32][8]
    double* qred = sred + 256;              // [32][8]
    float* wred = (float*)(qred + 256);     // [32][8]
    const int c = tid & 31, ch = tid >> 5;  // ch 0..7
    double s = 0.0, q = 0.0;
    #pragma unroll
    for (int j = 0; j < 16; ++j) {
      s += (double)ps_prev[c * 128 + ch * 16 + j];
      q += (double)pq_prev[c * 128 + ch * 16 + j];
    }
    float wb = 0.f;
    #pragma unroll
    for (int j = 0; j < 36; ++j) wb += fabsf(quant(wprev[c * 288 + ch * 36 + j]));
    sred[c * 8 + ch] = s;
    qred[c * 8 + ch] = q;
    wred[c * 8 + ch] = wb;
    __syncthreads();
    if (tid < 32) {
      double S = 0.0, Q = 0.0;
      float W = 0.f;
      #pragma unroll
      for (int j = 0; j < 8; ++j) {
        S += sred[tid * 8 + j];
        Q += qred[tid * 8 + j];
        W += wred[tid * 8 + j];
      }
      const double M = 32768.0;
      const double mu = S / M;
      const double var = Q / M - mu * mu;
      const double inv = 1.0 / sqrt(var + 1e-5);
      const double g = (double)gprev[tid];
      abuf[tid] = (float)(g * inv);
      bbuf[tid] = (float)((double)bprev[tid] + (double)(W * (1.f / 288.f)) - g * inv * mu);
    }
    __syncthreads();
  }

  // ---- stage x (transposed, swizzled). Each task: gather 4 rows of one col
  // via 4 coalesced global loads, one ds_write_b128 down the column.
  for (int i = tid; i < 32 * 34 * 3; i += 256) {
    const int ci = i / 102;
    const int r = i - ci * 102;
    const int cl = r / 3, k = r - cl * 3;   // cl: tile col, k: 16B block 0..2
    const int w = cl - 1;                   // global col (-1, 32, 33 -> pad)
    float4 v;
    float* vp = (float*)&v;
    #pragma unroll
    for (int t = 0; t < 4; ++t) {
      const int h = h0 - 1 + 4 * k + t;
      float xv = 0.f;
      if ((unsigned)h < 32u && (unsigned)w < 32u) {
        xv = in[((n * 32 + ci) * 32 + h) * 32 + w];
        if (AFFINE) xv = fmaxf(fmaf(abuf[ci], xv, bbuf[ci]), 0.f);
      }
      vp[t] = xv;
    }
    ((float4*)xs)[(ci * 34 + cl) * 4 + (k ^ (cl & 3))] = v;
  }
  // ---- stage + quantize weights for this co-octet (pair layout, 18/20 used)
  for (int i = tid; i < 2304; i += 256) {
    const int col = i / 288, r = i - col * 288;  // col = local co, r = ci*9+tap
    const int ci = r / 9, tap = r - ci * 9;
    const float q = quant(wraw[(oct * 8 + col) * 288 + r]);
    wls[((col >> 1) * 32 + ci) * 20 + tap * 2 + (col & 1)] = q;
  }
  __syncthreads();

  const int l = tid & 63, wv = tid >> 6;
  const int wcol = l & 31, rq = l >> 5;

  float acc[2][4];
  #pragma unroll
  for (int p = 0; p < 2; ++p)
    #pragma unroll
    for (int j = 0; j < 4; ++j) acc[p][j] = 0.f;

  const float4* xs4 = (const float4*)xs;
  const float2* xs2 = (const float2*)xs;

  for (int ci = 0; ci < 32; ++ci) {
    const float* wp = &wls[(wv * 32 + ci) * 20];
    const float4 w0 = ((const float4*)wp)[0];
    const float4 w1 = ((const float4*)wp)[1];
    const float4 w2 = ((const float4*)wp)[2];
    const float4 w3 = ((const float4*)wp)[3];
    const float2 w4 = *(const float2*)(wp + 16);
    // tap t: wA[t] (even co), wB[t] (odd co)
    const float wA[9] = {w0.x, w0.z, w1.x, w1.z, w2.x, w2.z, w3.x, w3.z, w4.x};
    const float wB[9] = {w0.y, w0.w, w1.y, w1.w, w2.y, w2.w, w3.y, w3.w, w4.y};
    #pragma unroll
    for (int d = 0; d < 3; ++d) {          // d = kw; tile col = wcol + d
      const int cl = wcol + d;
      const int cb = (ci * 34 + cl) * 4;
      const float4 lo = xs4[cb + (rq ^ (cl & 3))];           // words 4rq..4rq+3
      const float2 hi = xs2[(cb + ((rq + 1) ^ (cl & 3))) * 2]; // words 4rq+4,5
      const float v[6] = {lo.x, lo.y, lo.z, lo.w, hi.x, hi.y};
      #pragma unroll
      for (int kh = 0; kh < 3; ++kh) {
        const float a0 = wA[kh * 3 + d], b0 = wB[kh * 3 + d];
        #pragma unroll
        for (int j = 0; j < 4; ++j) {
          const float xv = v[j + kh];
          acc[0][j] += fabsf(xv - a0);
          acc[1][j] += fabsf(xv - b0);
        }
      }
    }
  }

  // ---- epilogue: write raw conv out + per-(co,block) stats
  #pragma unroll
  for (int p = 0; p < 2; ++p) {
    const int co = oct * 8 + wv * 2 + p;
    float s = 0.f, q = 0.f;
    #pragma unroll
    for (int j = 0; j < 4; ++j) {
      const float o = -acc[p][j];
      outb[((n * 32 + co) * 32 + (h0 + rq * 4 + j)) * 32 + wcol] = o;
      s += o;
      q += o * o;
    }
    #pragma unroll
    for (int d = 32; d; d >>= 1) {
      s += __shfl_xor(s, d);
      q += __shfl_xor(q, d);
    }
    if (l == 0) {
      ps_out[co * 128 + n * 4 + rg] = s;
      pq_out[co * 128 + n * 4 + rg] = q;
    }
  }
}

// ---- K3: redundant BN2 fold + relu(a2*o2 + b2 + x) ----
__global__ __launch_bounds__(256) void final_k(
    const float* __restrict__ o2, const float* __restrict__ xres,
    const float* __restrict__ ps, const float* __restrict__ pq,
    const float* __restrict__ w2raw, const float* __restrict__ g2,
    const float* __restrict__ b2, float* __restrict__ out) {
  __shared__ double sred[256], qred[256];
  __shared__ float wred[256];
  __shared__ float abuf[32], bbuf[32];
  const int tid = threadIdx.x;
  const int c = tid & 31, ch = tid >> 5;
  double s = 0.0, q = 0.0;
  #pragma unroll
  for (int j = 0; j < 16; ++j) {
    s += (double)ps[c * 128 + ch * 16 + j];
    q += (double)pq[c * 128 + ch * 16 + j];
  }
  float wb = 0.f;
  #pragma unroll
  for (int j = 0; j < 36; ++j) wb += fabsf(quant(w2raw[c * 288 + ch * 36 + j]));
  sred[c * 8 + ch] = s;
  qred[c * 8 + ch] = q;
  wred[c * 8 + ch] = wb;
  __syncthreads();
  if (tid < 32) {
    double S = 0.0, Q = 0.0;
    float W = 0.f;
    #pragma unroll
    for (int j = 0; j < 8; ++j) {
      S += sred[tid * 8 + j];
      Q += qred[tid * 8 + j];
      W += wred[tid * 8 + j];
    }
    const double M = 32768.0;
    const double mu = S / M;
    const double var = Q / M - mu * mu;
    const double inv = 1.0 / sqrt(var + 1e-5);
    const double g = (double)g2[tid];
    abuf[tid] = (float)(g * inv);
    bbuf[tid] = (float)((double)b2[tid] + (double)(W * (1.f / 288.f)) - g * inv * mu);
  }
  __syncthreads();

  const int base = blockIdx.x * 512;  // float4 units; 512 blocks x 512 = 262144
  for (int i = tid; i < 512; i += 256) {
    const int f4 = base + i;
    const int cc = (f4 >> 8) & 31;
    const float4 o = ((const float4*)o2)[f4];
    const float4 xr = ((const float4*)xres)[f4];
    const float av = abuf[cc], bv = bbuf[cc];
    float4 r;
    r.x = fmaxf(fmaf(av, o.x, bv) + xr.x, 0.f);
    r.y = fmaxf(fmaf(av, o.y, bv) + xr.y, 0.f);
    r.z = fmaxf(fmaf(av, o.z, bv) + xr.z, 0.f);
    r.w = fmaxf(fmaf(av, o.w, bv) + xr.w, 0.f);
    ((float4*)out)[f4] = r;
  }
}

extern "C" void kernel_launch(void* const* d_in, const int* in_sizes, int n_in,
                              void* d_out, int out_size, void* d_ws, size_t ws_size,
                              hipStream_t stream) {
  const float* x   = (const float*)d_in[0];
  const float* w1  = (const float*)d_in[1];
  const float* g1  = (const float*)d_in[2];
  const float* be1 = (const float*)d_in[3];
  const float* w2  = (const float*)d_in[4];
  const float* g2  = (const float*)d_in[5];
  const float* be2 = (const float*)d_in[6];
  float* ws = (float*)d_ws;

  float* PS1 = ws;                  // 4096
  float* PQ1 = ws + 4096;           // 4096
  float* PS2 = ws + 8192;           // 4096
  float* PQ2 = ws + 12288;          // 4096
  float* O1  = ws + 16384;          // 1048576 (16B aligned)
  float* O2  = O1 + 1048576;        // 1048576
  float* out = (float*)d_out;

  conv_k<false><<<512, 256, 0, stream>>>(x, w1, nullptr, nullptr, nullptr,
                                         nullptr, nullptr, O1, PS1, PQ1);
  conv_k<true><<<512, 256, 0, stream>>>(O1, w2, PS1, PQ1, w1, g1, be1,
                                        O2, PS2, PQ2);
  final_k<<<512, 256, 0, stream>>>(O2, x, PS2, PQ2, w2, g2, be2, out);
}